// Round 1
// baseline (259.741 us; speedup 1.0000x reference)
//
#include <hip/hip_runtime.h>
#include <hip/hip_bf16.h>
#include <cstdint>
#include <math.h>

// Problem constants
#define B_DIM 2
#define T_SEQ 2048
#define C_DIM 1024
#define H_NUM 16
#define D_HEAD 64
#define M_ROWS (B_DIM * T_SEQ)      // 4096
#define N_QKV (3 * H_NUM * D_HEAD)  // 3072

using short8  = __attribute__((ext_vector_type(8))) short;
using short4v = __attribute__((ext_vector_type(4))) short;
using f32x4   = __attribute__((ext_vector_type(4))) float;

__device__ __forceinline__ short f2bf(float f) {
  union { __hip_bfloat16 h; short s; } u;
  u.h = __float2bfloat16(f);
  return u.s;
}

// ---------------------------------------------------------------------------
// Kernel 1: f32 -> bf16 cast (vectorized, 8 elems/thread)
// ---------------------------------------------------------------------------
__global__ __launch_bounds__(256) void cvt_f32_bf16(const float* __restrict__ in,
                                                    short* __restrict__ out, int n8) {
  int i = blockIdx.x * 256 + threadIdx.x;
  if (i >= n8) return;
  const float4* p = reinterpret_cast<const float4*>(in) + (size_t)i * 2;
  float4 a = p[0], b = p[1];
  short8 o;
  o[0] = f2bf(a.x); o[1] = f2bf(a.y); o[2] = f2bf(a.z); o[3] = f2bf(a.w);
  o[4] = f2bf(b.x); o[5] = f2bf(b.y); o[6] = f2bf(b.z); o[7] = f2bf(b.w);
  reinterpret_cast<short8*>(out)[i] = o;
}

// ---------------------------------------------------------------------------
// Kernel 2: pack Wq/Wk/Wv [H][C][D] f32 -> Wt [3*H*D][C] bf16 (transposed)
// grid: 3 * H * (C/64) = 768 blocks, 256 threads
// ---------------------------------------------------------------------------
__global__ __launch_bounds__(256) void pack_w(const float* __restrict__ Wq,
                                              const float* __restrict__ Wk,
                                              const float* __restrict__ Wv,
                                              short* __restrict__ Wt) {
  int bid  = blockIdx.x;
  int proj = bid >> 8;          // 0..2  (bid / 256)
  int h    = (bid >> 4) & 15;   // 0..15
  int cb   = bid & 15;          // c block of 64
  const float* W = (proj == 0) ? Wq : ((proj == 1) ? Wk : Wv);
  const float* src = W + ((size_t)h * C_DIM + (size_t)cb * 64) * D_HEAD;

  __shared__ float tile[64][65];  // [c][d], padded
  int tid = threadIdx.x;

#pragma unroll
  for (int j = 0; j < 4; j++) {
    int flat = tid + j * 256;       // float4 index in 64x64 tile
    int c    = flat >> 4;           // /16
    int d4   = flat & 15;
    float4 v = reinterpret_cast<const float4*>(src + (size_t)c * D_HEAD)[d4];
    tile[c][d4 * 4 + 0] = v.x;
    tile[c][d4 * 4 + 1] = v.y;
    tile[c][d4 * 4 + 2] = v.z;
    tile[c][d4 * 4 + 3] = v.w;
  }
  __syncthreads();

  int d     = tid >> 2;          // 0..63
  int cpart = (tid & 3) * 16;    // 0,16,32,48
  short* dst = Wt + ((size_t)(proj * H_NUM + h) * D_HEAD + d) * C_DIM + cb * 64 + cpart;
  short8 o0, o1;
#pragma unroll
  for (int j = 0; j < 8; j++) {
    o0[j] = f2bf(tile[cpart + j][d]);
    o1[j] = f2bf(tile[cpart + 8 + j][d]);
  }
  *reinterpret_cast<short8*>(dst)     = o0;
  *reinterpret_cast<short8*>(dst + 8) = o1;
}

// ---------------------------------------------------------------------------
// GEMM: C[M,N] = A[M,K] @ Bt[N,K]^T, bf16 in, f32 accum.
// 128x128 tile, BK=32, 256 threads (4 waves, 2x2), 16x16x32 MFMA.
// MODE 0: epilogue scatters q,k as [B,H,T,D] bf16 and v transposed [B,H,D,T].
// MODE 1: epilogue adds bias, stores f32 row-major [M][N].
// ---------------------------------------------------------------------------
template <int MODE>
__global__ __launch_bounds__(256) void gemm_bt(
    const short* __restrict__ A, const short* __restrict__ Bt,
    const float* __restrict__ bias,
    short* __restrict__ qb, short* __restrict__ kb, short* __restrict__ vtb,
    float* __restrict__ outb,
    int M, int N, int K) {
  constexpr int BK  = 32;
  constexpr int LDT = 40;  // padded row (bf16 elems): 80B -> bank-conflict-free b128 reads
  __shared__ short As[128 * LDT];
  __shared__ short Bs[128 * LDT];

  int tid  = threadIdx.x;
  int lane = tid & 63;
  int wv   = tid >> 6;
  int ntn  = N >> 7;
  int bm   = blockIdx.x / ntn;
  int bn   = blockIdx.x % ntn;
  int row0 = bm << 7, col0 = bn << 7;
  int wm   = (wv >> 1) << 6;  // wave row offset in tile
  int wn   = (wv & 1) << 6;   // wave col offset in tile

  f32x4 acc[4][4];
#pragma unroll
  for (int i = 0; i < 4; i++)
#pragma unroll
    for (int j = 0; j < 4; j++) acc[i][j] = (f32x4){0.f, 0.f, 0.f, 0.f};

  // staging: each thread 2x16B per operand
  int sr = tid >> 2;          // 0..63
  int sc = (tid & 3) * 8;     // 0,8,16,24
  const short* ap = A  + (size_t)(row0 + sr) * K + sc;
  const short* bp = Bt + (size_t)(col0 + sr) * K + sc;
  short* as0 = &As[sr * LDT + sc];
  short* as1 = &As[(sr + 64) * LDT + sc];
  short* bs0 = &Bs[sr * LDT + sc];
  short* bs1 = &Bs[(sr + 64) * LDT + sc];
  const size_t rstep = (size_t)64 * K;

  for (int k0 = 0; k0 < K; k0 += BK) {
    short8 a0 = *reinterpret_cast<const short8*>(ap);
    short8 a1 = *reinterpret_cast<const short8*>(ap + rstep);
    short8 b0 = *reinterpret_cast<const short8*>(bp);
    short8 b1 = *reinterpret_cast<const short8*>(bp + rstep);
    __syncthreads();  // previous iteration's reads done
    *reinterpret_cast<short8*>(as0) = a0;
    *reinterpret_cast<short8*>(as1) = a1;
    *reinterpret_cast<short8*>(bs0) = b0;
    *reinterpret_cast<short8*>(bs1) = b1;
    __syncthreads();

    short8 af[4], bf[4];
#pragma unroll
    for (int mi = 0; mi < 4; mi++)
      af[mi] = *reinterpret_cast<const short8*>(
          &As[(wm + mi * 16 + (lane & 15)) * LDT + (lane >> 4) * 8]);
#pragma unroll
    for (int ni = 0; ni < 4; ni++)
      bf[ni] = *reinterpret_cast<const short8*>(
          &Bs[(wn + ni * 16 + (lane & 15)) * LDT + (lane >> 4) * 8]);
#pragma unroll
    for (int mi = 0; mi < 4; mi++)
#pragma unroll
      for (int ni = 0; ni < 4; ni++)
        acc[mi][ni] = __builtin_amdgcn_mfma_f32_16x16x32_bf16(af[mi], bf[ni],
                                                              acc[mi][ni], 0, 0, 0);
    ap += BK;
    bp += BK;
  }

  // epilogue: C/D layout: col = lane&15, row = (lane>>4)*4 + r
#pragma unroll
  for (int mi = 0; mi < 4; mi++) {
#pragma unroll
    for (int ni = 0; ni < 4; ni++) {
      int rb  = row0 + wm + mi * 16 + ((lane >> 4) << 2);
      int col = col0 + wn + ni * 16 + (lane & 15);
      f32x4 v = acc[mi][ni];
      if (MODE == 0) {
        int proj = col >> 10;
        int hh   = (col >> 6) & (H_NUM - 1);
        int d    = col & (D_HEAD - 1);
        int b    = rb >> 11;          // / T_SEQ
        int t    = rb & (T_SEQ - 1);
        if (proj < 2) {
          short* dst = (proj == 0 ? qb : kb) +
                       ((size_t)(b * H_NUM + hh) * T_SEQ) * D_HEAD + d;
#pragma unroll
          for (int r = 0; r < 4; r++)
            dst[(size_t)(t + r) * D_HEAD] = f2bf(v[r]);
        } else {
          short4v pk;
#pragma unroll
          for (int r = 0; r < 4; r++) pk[r] = f2bf(v[r]);
          short* dst = vtb + ((size_t)(b * H_NUM + hh) * D_HEAD + d) * T_SEQ + t;
          *reinterpret_cast<short4v*>(dst) = pk;
        }
      } else {
        float bb = bias[col];
#pragma unroll
        for (int r = 0; r < 4; r++)
          outb[(size_t)(rb + r) * N + col] = v[r] + bb;
      }
    }
  }
}

// ---------------------------------------------------------------------------
// Flash attention, causal. grid = B*H*(T/64) blocks, 256 threads (4 waves).
// Each wave: 16 q-rows. s-blocks of 32 staged in LDS (K row-major, V transposed).
// ---------------------------------------------------------------------------
__global__ __launch_bounds__(256) void attn_fwd(const short* __restrict__ q,
                                                const short* __restrict__ k,
                                                const short* __restrict__ vt,
                                                short* __restrict__ ob) {
  constexpr float LOG2E = 1.44269504f;
  int nq   = T_SEQ / 64;
  int bh   = blockIdx.x / nq;
  int qblk = blockIdx.x % nq;
  int b    = bh >> 4;
  int h    = bh & 15;
  int tid  = threadIdx.x, lane = tid & 63, wv = tid >> 6;
  int qr   = qblk * 64 + wv * 16;

  __shared__ short Kl[32][72];     // [s][d], +8 pad
  __shared__ short Vl[64][40];     // [d][s], +8 pad
  __shared__ short Pl[4][16][40];  // per-wave [t][s], +8 pad

  const short* qp = q  + (size_t)bh * T_SEQ * D_HEAD;
  const short* kp = k  + (size_t)bh * T_SEQ * D_HEAD;
  const short* vp = vt + (size_t)bh * D_HEAD * T_SEQ;

  short8 qf[2];
#pragma unroll
  for (int kk = 0; kk < 2; kk++)
    qf[kk] = *reinterpret_cast<const short8*>(
        qp + (size_t)(qr + (lane & 15)) * D_HEAD + kk * 32 + (lane >> 4) * 8);

  f32x4 acc[4];
#pragma unroll
  for (int i = 0; i < 4; i++) acc[i] = (f32x4){0.f, 0.f, 0.f, 0.f};
  float m_r[4] = {-INFINITY, -INFINITY, -INFINITY, -INFINITY};
  float l_r[4] = {0.f, 0.f, 0.f, 0.f};

  int sEnd = qblk * 64 + 64;
  int krow = tid >> 3, kcol = (tid & 7) * 8;  // K staging: 32 rows x 64
  int vrow = tid >> 2, vcol = (tid & 3) * 8;  // V staging: 64 rows x 32

  for (int s0 = 0; s0 < sEnd; s0 += 32) {
    __syncthreads();
    *reinterpret_cast<short8*>(&Kl[krow][kcol]) =
        *reinterpret_cast<const short8*>(kp + (size_t)(s0 + krow) * D_HEAD + kcol);
    *reinterpret_cast<short8*>(&Vl[vrow][vcol]) =
        *reinterpret_cast<const short8*>(vp + (size_t)vrow * T_SEQ + s0 + vcol);
    __syncthreads();

    // S = Q K^T   (two 16x16 tiles over 32 s-columns)
    f32x4 sa[2];
#pragma unroll
    for (int st = 0; st < 2; st++) {
      f32x4 s = (f32x4){0.f, 0.f, 0.f, 0.f};
#pragma unroll
      for (int kk = 0; kk < 2; kk++) {
        short8 kf = *reinterpret_cast<const short8*>(
            &Kl[st * 16 + (lane & 15)][kk * 32 + (lane >> 4) * 8]);
        s = __builtin_amdgcn_mfma_f32_16x16x32_bf16(qf[kk], kf, s, 0, 0, 0);
      }
      sa[st] = s;
    }

    // scale + causal mask (keep col <= row)
    float sv[2][4];
    int rb = qr + ((lane >> 4) << 2);
    int cb = s0 + (lane & 15);
#pragma unroll
    for (int st = 0; st < 2; st++)
#pragma unroll
      for (int r = 0; r < 4; r++) {
        float x = sa[st][r] * 0.125f;
        sv[st][r] = (cb + st * 16 <= rb + r) ? x : -INFINITY;
      }

    // online softmax per row r (row-reduce across the 16-lane group)
#pragma unroll
    for (int r = 0; r < 4; r++) {
      float mx = fmaxf(sv[0][r], sv[1][r]);
#pragma unroll
      for (int off = 1; off < 16; off <<= 1) mx = fmaxf(mx, __shfl_xor(mx, off));
      float mnew = fmaxf(m_r[r], mx);
      float sc   = exp2f((m_r[r] - mnew) * LOG2E);
      m_r[r] = mnew;
      float ps = 0.f;
#pragma unroll
      for (int st = 0; st < 2; st++) {
        float p = exp2f((sv[st][r] - mnew) * LOG2E);
        ps += p;
        Pl[wv][((lane >> 4) << 2) + r][st * 16 + (lane & 15)] = f2bf(p);
      }
#pragma unroll
      for (int off = 1; off < 16; off <<= 1) ps += __shfl_xor(ps, off);
      l_r[r] = l_r[r] * sc + ps;
#pragma unroll
      for (int ni = 0; ni < 4; ni++) acc[ni][r] *= sc;
    }

    // PV: O += P[16x32] @ V[32x64]
    short8 pf = *reinterpret_cast<const short8*>(&Pl[wv][lane & 15][(lane >> 4) * 8]);
#pragma unroll
    for (int ni = 0; ni < 4; ni++) {
      short8 vf = *reinterpret_cast<const short8*>(
          &Vl[ni * 16 + (lane & 15)][(lane >> 4) * 8]);
      acc[ni] = __builtin_amdgcn_mfma_f32_16x16x32_bf16(pf, vf, acc[ni], 0, 0, 0);
    }
  }

  // epilogue: divide by l, store to ob[B*T][C] with feature = h*64 + d
#pragma unroll
  for (int ni = 0; ni < 4; ni++)
#pragma unroll
    for (int r = 0; r < 4; r++) {
      float o = acc[ni][r] / l_r[r];
      int t   = qr + ((lane >> 4) << 2) + r;
      int cc  = h * D_HEAD + ni * 16 + (lane & 15);
      ob[(size_t)(b * T_SEQ + t) * C_DIM + cc] = f2bf(o);
    }
}

// ---------------------------------------------------------------------------
// Launch. Workspace layout (needs >= 40 MB):
//   [0, 8M)        xb   bf16 x cast            (reused as obuf after QKV GEMM)
//   [8M, 14.3M)    Wt   bf16 packed QKV weights [3072][1024]
//   [14M, 16M)     Wob  bf16 Wo [1024][1024]
//   [16M, 24M)     qb   bf16 [B,H,T,D]
//   [24M, 32M)     kb   bf16 [B,H,T,D]
//   [32M, 40M)     vtb  bf16 [B,H,D,T]
// ---------------------------------------------------------------------------
extern "C" void kernel_launch(void* const* d_in, const int* in_sizes, int n_in,
                              void* d_out, int out_size, void* d_ws, size_t ws_size,
                              hipStream_t stream) {
  const float* x  = (const float*)d_in[0];
  const float* Wq = (const float*)d_in[1];
  const float* Wk = (const float*)d_in[2];
  const float* Wv = (const float*)d_in[3];
  const float* Wo = (const float*)d_in[4];
  const float* bo = (const float*)d_in[5];
  float* out = (float*)d_out;

  char* ws = (char*)d_ws;
  short* xb   = (short*)(ws + 0);
  short* Wt   = (short*)(ws + 8388608);
  short* Wob  = (short*)(ws + 14680064);
  short* qb   = (short*)(ws + 16777216);
  short* kb   = (short*)(ws + 25165824);
  short* vtb  = (short*)(ws + 33554432);
  short* obuf = xb;  // reuse after QKV GEMM consumed xb

  cvt_f32_bf16<<<2048, 256, 0, stream>>>(x, xb, M_ROWS * C_DIM / 8);
  cvt_f32_bf16<<<512, 256, 0, stream>>>(Wo, Wob, C_DIM * C_DIM / 8);
  pack_w<<<768, 256, 0, stream>>>(Wq, Wk, Wv, Wt);

  gemm_bt<0><<<(M_ROWS / 128) * (N_QKV / 128), 256, 0, stream>>>(
      xb, Wt, nullptr, qb, kb, vtb, nullptr, M_ROWS, N_QKV, C_DIM);

  attn_fwd<<<B_DIM * H_NUM * (T_SEQ / 64), 256, 0, stream>>>(qb, kb, vtb, obuf);

  gemm_bt<1><<<(M_ROWS / 128) * (C_DIM / 128), 256, 0, stream>>>(
      obuf, Wob, bo, nullptr, nullptr, nullptr, out, M_ROWS, C_DIM, C_DIM);
}

// Round 2
// 211.069 us; speedup vs baseline: 1.2306x; 1.2306x over previous
//
#include <hip/hip_runtime.h>
#include <hip/hip_bf16.h>
#include <cstdint>
#include <math.h>

// Problem constants
#define B_DIM 2
#define T_SEQ 2048
#define C_DIM 1024
#define H_NUM 16
#define D_HEAD 64
#define M_ROWS (B_DIM * T_SEQ)      // 4096
#define N_QKV (3 * H_NUM * D_HEAD)  // 3072

using short8  = __attribute__((ext_vector_type(8))) short;
using short4v = __attribute__((ext_vector_type(4))) short;
using f32x4   = __attribute__((ext_vector_type(4))) float;

__device__ __forceinline__ short f2bf(float f) {
  union { __hip_bfloat16 h; short s; } u;
  u.h = __float2bfloat16(f);
  return u.s;
}

// ---------------------------------------------------------------------------
// Kernel 1: f32 -> bf16 cast (vectorized, 8 elems/thread)
// ---------------------------------------------------------------------------
__global__ __launch_bounds__(256) void cvt_f32_bf16(const float* __restrict__ in,
                                                    short* __restrict__ out, int n8) {
  int i = blockIdx.x * 256 + threadIdx.x;
  if (i >= n8) return;
  const float4* p = reinterpret_cast<const float4*>(in) + (size_t)i * 2;
  float4 a = p[0], b = p[1];
  short8 o;
  o[0] = f2bf(a.x); o[1] = f2bf(a.y); o[2] = f2bf(a.z); o[3] = f2bf(a.w);
  o[4] = f2bf(b.x); o[5] = f2bf(b.y); o[6] = f2bf(b.z); o[7] = f2bf(b.w);
  reinterpret_cast<short8*>(out)[i] = o;
}

// ---------------------------------------------------------------------------
// Kernel 2: pack Wq/Wk/Wv [H][C][D] f32 -> Wt [3*H*D][C] bf16 (transposed)
// ---------------------------------------------------------------------------
__global__ __launch_bounds__(256) void pack_w(const float* __restrict__ Wq,
                                              const float* __restrict__ Wk,
                                              const float* __restrict__ Wv,
                                              short* __restrict__ Wt) {
  int bid  = blockIdx.x;
  int proj = bid >> 8;
  int h    = (bid >> 4) & 15;
  int cb   = bid & 15;
  const float* W = (proj == 0) ? Wq : ((proj == 1) ? Wk : Wv);
  const float* src = W + ((size_t)h * C_DIM + (size_t)cb * 64) * D_HEAD;

  __shared__ float tile[64][65];
  int tid = threadIdx.x;

#pragma unroll
  for (int j = 0; j < 4; j++) {
    int flat = tid + j * 256;
    int c    = flat >> 4;
    int d4   = flat & 15;
    float4 v = reinterpret_cast<const float4*>(src + (size_t)c * D_HEAD)[d4];
    tile[c][d4 * 4 + 0] = v.x;
    tile[c][d4 * 4 + 1] = v.y;
    tile[c][d4 * 4 + 2] = v.z;
    tile[c][d4 * 4 + 3] = v.w;
  }
  __syncthreads();

  int d     = tid >> 2;
  int cpart = (tid & 3) * 16;
  short* dst = Wt + ((size_t)(proj * H_NUM + h) * D_HEAD + d) * C_DIM + cb * 64 + cpart;
  short8 o0, o1;
#pragma unroll
  for (int j = 0; j < 8; j++) {
    o0[j] = f2bf(tile[cpart + j][d]);
    o1[j] = f2bf(tile[cpart + 8 + j][d]);
  }
  *reinterpret_cast<short8*>(dst)     = o0;
  *reinterpret_cast<short8*>(dst + 8) = o1;
}

// ---------------------------------------------------------------------------
// GEMM: C[M,N] = A[M,K] @ Bt[N,K]^T, bf16 in, f32 accum. (unchanged)
// ---------------------------------------------------------------------------
template <int MODE>
__global__ __launch_bounds__(256) void gemm_bt(
    const short* __restrict__ A, const short* __restrict__ Bt,
    const float* __restrict__ bias,
    short* __restrict__ qb, short* __restrict__ kb, short* __restrict__ vtb,
    float* __restrict__ outb,
    int M, int N, int K) {
  constexpr int BK  = 32;
  constexpr int LDT = 40;
  __shared__ short As[128 * LDT];
  __shared__ short Bs[128 * LDT];

  int tid  = threadIdx.x;
  int lane = tid & 63;
  int wv   = tid >> 6;
  int ntn  = N >> 7;
  int bm   = blockIdx.x / ntn;
  int bn   = blockIdx.x % ntn;
  int row0 = bm << 7, col0 = bn << 7;
  int wm   = (wv >> 1) << 6;
  int wn   = (wv & 1) << 6;

  f32x4 acc[4][4];
#pragma unroll
  for (int i = 0; i < 4; i++)
#pragma unroll
    for (int j = 0; j < 4; j++) acc[i][j] = (f32x4){0.f, 0.f, 0.f, 0.f};

  int sr = tid >> 2;
  int sc = (tid & 3) * 8;
  const short* ap = A  + (size_t)(row0 + sr) * K + sc;
  const short* bp = Bt + (size_t)(col0 + sr) * K + sc;
  short* as0 = &As[sr * LDT + sc];
  short* as1 = &As[(sr + 64) * LDT + sc];
  short* bs0 = &Bs[sr * LDT + sc];
  short* bs1 = &Bs[(sr + 64) * LDT + sc];
  const size_t rstep = (size_t)64 * K;

  for (int k0 = 0; k0 < K; k0 += BK) {
    short8 a0 = *reinterpret_cast<const short8*>(ap);
    short8 a1 = *reinterpret_cast<const short8*>(ap + rstep);
    short8 b0 = *reinterpret_cast<const short8*>(bp);
    short8 b1 = *reinterpret_cast<const short8*>(bp + rstep);
    __syncthreads();
    *reinterpret_cast<short8*>(as0) = a0;
    *reinterpret_cast<short8*>(as1) = a1;
    *reinterpret_cast<short8*>(bs0) = b0;
    *reinterpret_cast<short8*>(bs1) = b1;
    __syncthreads();

    short8 af[4], bf[4];
#pragma unroll
    for (int mi = 0; mi < 4; mi++)
      af[mi] = *reinterpret_cast<const short8*>(
          &As[(wm + mi * 16 + (lane & 15)) * LDT + (lane >> 4) * 8]);
#pragma unroll
    for (int ni = 0; ni < 4; ni++)
      bf[ni] = *reinterpret_cast<const short8*>(
          &Bs[(wn + ni * 16 + (lane & 15)) * LDT + (lane >> 4) * 8]);
#pragma unroll
    for (int mi = 0; mi < 4; mi++)
#pragma unroll
      for (int ni = 0; ni < 4; ni++)
        acc[mi][ni] = __builtin_amdgcn_mfma_f32_16x16x32_bf16(af[mi], bf[ni],
                                                              acc[mi][ni], 0, 0, 0);
    ap += BK;
    bp += BK;
  }

#pragma unroll
  for (int mi = 0; mi < 4; mi++) {
#pragma unroll
    for (int ni = 0; ni < 4; ni++) {
      int rb  = row0 + wm + mi * 16 + ((lane >> 4) << 2);
      int col = col0 + wn + ni * 16 + (lane & 15);
      f32x4 v = acc[mi][ni];
      if (MODE == 0) {
        int proj = col >> 10;
        int hh   = (col >> 6) & (H_NUM - 1);
        int d    = col & (D_HEAD - 1);
        int b    = rb >> 11;
        int t    = rb & (T_SEQ - 1);
        if (proj < 2) {
          short* dst = (proj == 0 ? qb : kb) +
                       ((size_t)(b * H_NUM + hh) * T_SEQ) * D_HEAD + d;
#pragma unroll
          for (int r = 0; r < 4; r++)
            dst[(size_t)(t + r) * D_HEAD] = f2bf(v[r]);
        } else {
          short4v pk;
#pragma unroll
          for (int r = 0; r < 4; r++) pk[r] = f2bf(v[r]);
          short* dst = vtb + ((size_t)(b * H_NUM + hh) * D_HEAD + d) * T_SEQ + t;
          *reinterpret_cast<short4v*>(dst) = pk;
        }
      } else {
        float bb = bias[col];
#pragma unroll
        for (int r = 0; r < 4; r++)
          outb[(size_t)(rb + r) * N + col] = v[r] + bb;
      }
    }
  }
}

// ---------------------------------------------------------------------------
// Flash attention v2: swapped-operand (S^T = K·Q^T), no LDS staging, no
// main-loop barriers. 4 waves/block, 32 q-rows/wave (2 q-tiles), KV chunk 64.
// K/V fragments read directly from global (L2-resident per head; grid ordered
// qblk-major so a head's blocks share an XCD L2).
// PV uses 16x16x16 MFMA: its B-operand k-mapping (k=g*4+j) equals the D-output
// row-mapping of the S^T tile, so P needs no cross-lane rearrangement.
// ---------------------------------------------------------------------------
__global__ __launch_bounds__(256) void attn_fwd(const short* __restrict__ qg,
                                                const short* __restrict__ kg,
                                                const short* __restrict__ vt,
                                                short* __restrict__ ob) {
  constexpr float LOG2E = 1.44269504f;
  constexpr float SCALE = 0.125f;  // 1/sqrt(64)
  int bh   = blockIdx.x & 31;   // qblk-major: all 16 blocks of a head -> same XCD
  int qblk = blockIdx.x >> 5;   // 0..15
  int b    = bh >> 4;
  int h    = bh & 15;
  int tid  = threadIdx.x, lane = tid & 63, wv = tid >> 6;
  int q15  = lane & 15, g = lane >> 4;
  int qr   = qblk * 128 + wv * 32;  // wave's first q row

  const short* qp = qg + (size_t)bh * T_SEQ * D_HEAD;
  const short* kp = kg + (size_t)bh * T_SEQ * D_HEAD;
  const short* vp = vt + (size_t)bh * D_HEAD * T_SEQ;

  // Q fragments (B operand of S^T mfma): lane&15 = q, elems over d
  short8 qf[2][2];
#pragma unroll
  for (int qt = 0; qt < 2; qt++)
#pragma unroll
    for (int kk = 0; kk < 2; kk++)
      qf[qt][kk] = *reinterpret_cast<const short8*>(
          qp + (size_t)(qr + qt * 16 + q15) * D_HEAD + kk * 32 + g * 8);

  f32x4 acc[2][4];  // [qt][dt]: O^T, col=q, row=d
#pragma unroll
  for (int qt = 0; qt < 2; qt++)
#pragma unroll
    for (int dt = 0; dt < 4; dt++) acc[qt][dt] = (f32x4){0.f, 0.f, 0.f, 0.f};
  float m_[2] = {-1e30f, -1e30f};
  float l_[2] = {0.f, 0.f};

  auto process = [&](int s0, bool masked) {
    // S^T = K·Q^T: D[row=s][col=q]
    f32x4 sv[2][4];  // [qt][st]
#pragma unroll
    for (int st = 0; st < 4; st++) {
      const short* krow = kp + (size_t)(s0 + st * 16 + q15) * D_HEAD + g * 8;
      short8 kf0 = *reinterpret_cast<const short8*>(krow);
      short8 kf1 = *reinterpret_cast<const short8*>(krow + 32);
#pragma unroll
      for (int qt = 0; qt < 2; qt++) {
        f32x4 s = (f32x4){0.f, 0.f, 0.f, 0.f};
        s = __builtin_amdgcn_mfma_f32_16x16x32_bf16(kf0, qf[qt][0], s, 0, 0, 0);
        s = __builtin_amdgcn_mfma_f32_16x16x32_bf16(kf1, qf[qt][1], s, 0, 0, 0);
        sv[qt][st] = s;
      }
    }
    // scale + causal mask (s <= q)
#pragma unroll
    for (int qt = 0; qt < 2; qt++)
#pragma unroll
      for (int st = 0; st < 4; st++)
#pragma unroll
        for (int r = 0; r < 4; r++) {
          float x = sv[qt][st][r] * SCALE;
          if (masked) {
            int sg = s0 + st * 16 + g * 4 + r;
            if (sg > qr + qt * 16 + q15) x = -1e30f;
          }
          sv[qt][st][r] = x;
        }
    // online softmax per q-tile (lane-local + 2 shfl)
    short4v pb[2][4];
#pragma unroll
    for (int qt = 0; qt < 2; qt++) {
      float mx = sv[qt][0][0];
#pragma unroll
      for (int st = 0; st < 4; st++)
#pragma unroll
        for (int r = 0; r < 4; r++) mx = fmaxf(mx, sv[qt][st][r]);
      mx = fmaxf(mx, __shfl_xor(mx, 16));
      mx = fmaxf(mx, __shfl_xor(mx, 32));
      float mnew = fmaxf(m_[qt], mx);
      float sc   = __builtin_amdgcn_exp2f((m_[qt] - mnew) * LOG2E);
      m_[qt] = mnew;
      float ps = 0.f;
#pragma unroll
      for (int st = 0; st < 4; st++) {
#pragma unroll
        for (int r = 0; r < 4; r++) {
          float p = __builtin_amdgcn_exp2f((sv[qt][st][r] - mnew) * LOG2E);
          ps += p;
          pb[qt][st][r] = f2bf(p);
        }
      }
      ps += __shfl_xor(ps, 16);
      ps += __shfl_xor(ps, 32);
      l_[qt] = l_[qt] * sc + ps;
#pragma unroll
      for (int dt = 0; dt < 4; dt++) acc[qt][dt] *= sc;
    }
    // PV: O^T[d][q] += V^T[d][s] · P^T[s][q], 16-s tiles
#pragma unroll
    for (int st = 0; st < 4; st++)
#pragma unroll
      for (int dt = 0; dt < 4; dt++) {
        short4v vf = *reinterpret_cast<const short4v*>(
            vp + (size_t)(dt * 16 + q15) * T_SEQ + s0 + st * 16 + g * 4);
#pragma unroll
        for (int qt = 0; qt < 2; qt++) {
#if __has_builtin(__builtin_amdgcn_mfma_f32_16x16x16bf16_1k)
          acc[qt][dt] = __builtin_amdgcn_mfma_f32_16x16x16bf16_1k(
              vf, pb[qt][st], acc[qt][dt], 0, 0, 0);
#else
          // zero-padded k=32 fallback: data at k=8g+j (j<4), zeros elsewhere
          short8 az = (short8){vf[0], vf[1], vf[2], vf[3], 0, 0, 0, 0};
          short8 bz = (short8){pb[qt][st][0], pb[qt][st][1], pb[qt][st][2],
                               pb[qt][st][3], 0, 0, 0, 0};
          acc[qt][dt] =
              __builtin_amdgcn_mfma_f32_16x16x32_bf16(az, bz, acc[qt][dt], 0, 0, 0);
#endif
        }
      }
  };

  int s0 = 0;
  for (; s0 + 64 <= qr; s0 += 64) process(s0, false);
  process(s0, true);  // single masked chunk at qr & ~63

  // epilogue: per-wave LDS transpose -> coalesced bf16 stores
  __shared__ short Ol[4][32][68];
#pragma unroll
  for (int qt = 0; qt < 2; qt++) {
    float inv = 1.0f / l_[qt];
#pragma unroll
    for (int dt = 0; dt < 4; dt++)
#pragma unroll
      for (int r = 0; r < 4; r++)
        Ol[wv][qt * 16 + q15][dt * 16 + g * 4 + r] = f2bf(acc[qt][dt][r] * inv);
  }
  __syncthreads();
  int row = lane >> 1, cb = (lane & 1) * 32;
  size_t base = ((size_t)(b * T_SEQ) + qr + row) * C_DIM + h * 64 + cb;
#pragma unroll
  for (int i = 0; i < 4; i++)
    *reinterpret_cast<short8*>(ob + base + i * 8) =
        *reinterpret_cast<const short8*>(&Ol[wv][row][cb + i * 8]);
}

// ---------------------------------------------------------------------------
// Launch. Workspace layout (needs >= 40 MB):
//   [0, 8M)        xb   bf16 x cast            (reused as obuf after QKV GEMM)
//   [8M, 14.3M)    Wt   bf16 packed QKV weights [3072][1024]
//   [14M, 16M)     Wob  bf16 Wo [1024][1024]
//   [16M, 24M)     qb   bf16 [B,H,T,D]
//   [24M, 32M)     kb   bf16 [B,H,T,D]
//   [32M, 40M)     vtb  bf16 [B,H,D,T]
// ---------------------------------------------------------------------------
extern "C" void kernel_launch(void* const* d_in, const int* in_sizes, int n_in,
                              void* d_out, int out_size, void* d_ws, size_t ws_size,
                              hipStream_t stream) {
  const float* x  = (const float*)d_in[0];
  const float* Wq = (const float*)d_in[1];
  const float* Wk = (const float*)d_in[2];
  const float* Wv = (const float*)d_in[3];
  const float* Wo = (const float*)d_in[4];
  const float* bo = (const float*)d_in[5];
  float* out = (float*)d_out;

  char* ws = (char*)d_ws;
  short* xb   = (short*)(ws + 0);
  short* Wt   = (short*)(ws + 8388608);
  short* Wob  = (short*)(ws + 14680064);
  short* qb   = (short*)(ws + 16777216);
  short* kb   = (short*)(ws + 25165824);
  short* vtb  = (short*)(ws + 33554432);
  short* obuf = xb;  // reuse after QKV GEMM consumed xb

  cvt_f32_bf16<<<2048, 256, 0, stream>>>(x, xb, M_ROWS * C_DIM / 8);
  cvt_f32_bf16<<<512, 256, 0, stream>>>(Wo, Wob, C_DIM * C_DIM / 8);
  pack_w<<<768, 256, 0, stream>>>(Wq, Wk, Wv, Wt);

  gemm_bt<0><<<(M_ROWS / 128) * (N_QKV / 128), 256, 0, stream>>>(
      xb, Wt, nullptr, qb, kb, vtb, nullptr, M_ROWS, N_QKV, C_DIM);

  attn_fwd<<<B_DIM * H_NUM * (T_SEQ / 128), 256, 0, stream>>>(qb, kb, vtb, obuf);

  gemm_bt<1><<<(M_ROWS / 128) * (C_DIM / 128), 256, 0, stream>>>(
      obuf, Wob, bo, nullptr, nullptr, nullptr, out, M_ROWS, C_DIM, C_DIM);
}

// Round 3
// 173.159 us; speedup vs baseline: 1.5000x; 1.2189x over previous
//
#include <hip/hip_runtime.h>
#include <hip/hip_bf16.h>
#include <cstdint>
#include <math.h>

// Problem constants
#define B_DIM 2
#define T_SEQ 2048
#define C_DIM 1024
#define H_NUM 16
#define D_HEAD 64
#define M_ROWS (B_DIM * T_SEQ)      // 4096
#define N_QKV (3 * H_NUM * D_HEAD)  // 3072

using short8  = __attribute__((ext_vector_type(8))) short;
using short4v = __attribute__((ext_vector_type(4))) short;
using f32x4   = __attribute__((ext_vector_type(4))) float;

__device__ __forceinline__ short f2bf(float f) {
  union { __hip_bfloat16 h; short s; } u;
  u.h = __float2bfloat16(f);
  return u.s;
}

// async global->LDS, 16B per lane. LDS dest must be wave-uniform base + lane*16.
__device__ __forceinline__ void gld_lds16(short* lds, const short* g) {
  __builtin_amdgcn_global_load_lds(
      (const unsigned int __attribute__((address_space(1)))*)g,
      (unsigned int __attribute__((address_space(3)))*)lds, 16, 0, 0);
}

// ---------------------------------------------------------------------------
// Kernel 1: f32 -> bf16 cast (vectorized, 8 elems/thread)
// ---------------------------------------------------------------------------
__global__ __launch_bounds__(256) void cvt_f32_bf16(const float* __restrict__ in,
                                                    short* __restrict__ out, int n8) {
  int i = blockIdx.x * 256 + threadIdx.x;
  if (i >= n8) return;
  const float4* p = reinterpret_cast<const float4*>(in) + (size_t)i * 2;
  float4 a = p[0], b = p[1];
  short8 o;
  o[0] = f2bf(a.x); o[1] = f2bf(a.y); o[2] = f2bf(a.z); o[3] = f2bf(a.w);
  o[4] = f2bf(b.x); o[5] = f2bf(b.y); o[6] = f2bf(b.z); o[7] = f2bf(b.w);
  reinterpret_cast<short8*>(out)[i] = o;
}

// ---------------------------------------------------------------------------
// Kernel 2: pack Wq/Wk/Wv [H][C][D] f32 -> Wt [3*H*D][C] bf16 (transposed)
// ---------------------------------------------------------------------------
__global__ __launch_bounds__(256) void pack_w(const float* __restrict__ Wq,
                                              const float* __restrict__ Wk,
                                              const float* __restrict__ Wv,
                                              short* __restrict__ Wt) {
  int bid  = blockIdx.x;
  int proj = bid >> 8;
  int h    = (bid >> 4) & 15;
  int cb   = bid & 15;
  const float* W = (proj == 0) ? Wq : ((proj == 1) ? Wk : Wv);
  const float* src = W + ((size_t)h * C_DIM + (size_t)cb * 64) * D_HEAD;

  __shared__ float tile[64][65];
  int tid = threadIdx.x;

#pragma unroll
  for (int j = 0; j < 4; j++) {
    int flat = tid + j * 256;
    int c    = flat >> 4;
    int d4   = flat & 15;
    float4 v = reinterpret_cast<const float4*>(src + (size_t)c * D_HEAD)[d4];
    tile[c][d4 * 4 + 0] = v.x;
    tile[c][d4 * 4 + 1] = v.y;
    tile[c][d4 * 4 + 2] = v.z;
    tile[c][d4 * 4 + 3] = v.w;
  }
  __syncthreads();

  int d     = tid >> 2;
  int cpart = (tid & 3) * 16;
  short* dst = Wt + ((size_t)(proj * H_NUM + h) * D_HEAD + d) * C_DIM + cb * 64 + cpart;
  short8 o0, o1;
#pragma unroll
  for (int j = 0; j < 8; j++) {
    o0[j] = f2bf(tile[cpart + j][d]);
    o1[j] = f2bf(tile[cpart + 8 + j][d]);
  }
  *reinterpret_cast<short8*>(dst)     = o0;
  *reinterpret_cast<short8*>(dst + 8) = o1;
}

// ---------------------------------------------------------------------------
// GEMM: C[M,N] = A[M,K] @ Bt[N,K]^T, bf16 in, f32 accum.
// m97 structure: 128x128 tile, BK=32, linear LDS, global_load_lds width-16
// staging (2 issues/operand/K-step), 4 waves (2x2), 16x16x32 MFMA.
// MODE 0: epilogue scatters q (prescaled by 1/8), k as [B,H,T,D] bf16 and
//         v transposed [B,H,D,T]. MODE 1: adds bias, stores f32 [M][N].
// ---------------------------------------------------------------------------
template <int MODE>
__global__ __launch_bounds__(256) void gemm_bt(
    const short* __restrict__ A, const short* __restrict__ Bt,
    const float* __restrict__ bias,
    short* __restrict__ qb, short* __restrict__ kb, short* __restrict__ vtb,
    float* __restrict__ outb,
    int M, int N, int K) {
  constexpr int BK = 32;
  __shared__ short As[128 * BK];  // 8 KB, linear [row][32]
  __shared__ short Bs[128 * BK];

  int tid  = threadIdx.x;
  int lane = tid & 63;
  int wv   = tid >> 6;
  int q15  = lane & 15, g = lane >> 4;
  int ntn  = N >> 7;
  int bm   = blockIdx.x / ntn;
  int bn   = blockIdx.x % ntn;
  int row0 = bm << 7, col0 = bn << 7;
  int wm   = (wv >> 1) << 6;
  int wn   = (wv & 1) << 6;

  f32x4 acc[4][4];
#pragma unroll
  for (int i = 0; i < 4; i++)
#pragma unroll
    for (int j = 0; j < 4; j++) acc[i][j] = (f32x4){0.f, 0.f, 0.f, 0.f};

  // staging: thread -> (row = tid>>2, 16B chunk = tid&3); LDS byte off = tid*16
  const short* ag = A  + (size_t)(row0 + (tid >> 2)) * K + (tid & 3) * 8;
  const short* bg = Bt + (size_t)(col0 + (tid >> 2)) * K + (tid & 3) * 8;
  short* as = As + tid * 8;
  short* bs = Bs + tid * 8;
  const size_t gstep = (size_t)64 * K;

  for (int k0 = 0; k0 < K; k0 += BK) {
    __syncthreads();  // previous iteration's LDS reads done
    gld_lds16(as, ag);
    gld_lds16(as + 64 * BK, ag + gstep);
    gld_lds16(bs, bg);
    gld_lds16(bs + 64 * BK, bg + gstep);
    __syncthreads();  // compiler drains vmcnt(0) before s_barrier

    short8 af[4], bf[4];
#pragma unroll
    for (int mi = 0; mi < 4; mi++)
      af[mi] = *reinterpret_cast<const short8*>(&As[(wm + mi * 16 + q15) * BK + g * 8]);
#pragma unroll
    for (int ni = 0; ni < 4; ni++)
      bf[ni] = *reinterpret_cast<const short8*>(&Bs[(wn + ni * 16 + q15) * BK + g * 8]);
    __builtin_amdgcn_s_setprio(1);
#pragma unroll
    for (int mi = 0; mi < 4; mi++)
#pragma unroll
      for (int ni = 0; ni < 4; ni++)
        acc[mi][ni] = __builtin_amdgcn_mfma_f32_16x16x32_bf16(af[mi], bf[ni],
                                                              acc[mi][ni], 0, 0, 0);
    __builtin_amdgcn_s_setprio(0);
    ag += BK;
    bg += BK;
  }

  // epilogue: C/D layout: col = lane&15, row = (lane>>4)*4 + r
#pragma unroll
  for (int mi = 0; mi < 4; mi++) {
#pragma unroll
    for (int ni = 0; ni < 4; ni++) {
      int rb  = row0 + wm + mi * 16 + (g << 2);
      int col = col0 + wn + ni * 16 + q15;
      f32x4 v = acc[mi][ni];
      if (MODE == 0) {
        int proj = col >> 10;
        int hh   = (col >> 6) & (H_NUM - 1);
        int d    = col & (D_HEAD - 1);
        int b    = rb >> 11;
        int t    = rb & (T_SEQ - 1);
        if (proj < 2) {
          float scl = (proj == 0) ? 0.125f : 1.0f;  // fold 1/sqrt(D) into q
          short* dst = (proj == 0 ? qb : kb) +
                       ((size_t)(b * H_NUM + hh) * T_SEQ) * D_HEAD + d;
#pragma unroll
          for (int r = 0; r < 4; r++)
            dst[(size_t)(t + r) * D_HEAD] = f2bf(v[r] * scl);
        } else {
          short4v pk;
#pragma unroll
          for (int r = 0; r < 4; r++) pk[r] = f2bf(v[r]);
          short* dst = vtb + ((size_t)(b * H_NUM + hh) * D_HEAD + d) * T_SEQ + t;
          *reinterpret_cast<short4v*>(dst) = pk;
        }
      } else {
        float bb = bias[col];
#pragma unroll
        for (int r = 0; r < 4; r++)
          outb[(size_t)(rb + r) * N + col] = v[r] + bb;
      }
    }
  }
}

// ---------------------------------------------------------------------------
// Flash attention v3: swapped-operand (S^T = K·Q^T), registers only, K
// double-buffered across chunks, V issued before softmax. Heavy-first
// XCD-local dispatch. 4 waves/block, 32 q-rows/wave, KV chunk 64.
// ---------------------------------------------------------------------------
__global__ __launch_bounds__(256) void attn_fwd(const short* __restrict__ qg,
                                                const short* __restrict__ kg,
                                                const short* __restrict__ vt,
                                                short* __restrict__ ob) {
  constexpr float LOG2E = 1.44269504f;
  // dispatch: xcd = bid&7 (round-robin), 4 heads per XCD (KV 2MB < L2),
  // qblk descending so heavy blocks start first.
  int bid  = blockIdx.x;
  int slot = bid >> 3;
  int bh   = (bid & 7) * 4 + (slot & 3);
  int qblk = 15 - (slot >> 2);
  int b    = bh >> 4;
  int h    = bh & 15;
  int tid  = threadIdx.x, lane = tid & 63, wv = tid >> 6;
  int q15  = lane & 15, g = lane >> 4;
  int qr   = qblk * 128 + wv * 32;  // wave's first q row

  const short* qp = qg + (size_t)bh * T_SEQ * D_HEAD;
  const short* kp = kg + (size_t)bh * T_SEQ * D_HEAD;
  const short* vp = vt + (size_t)bh * D_HEAD * T_SEQ;

  // Q fragments (B operand of S^T mfma): lane&15 = q, elems over d (prescaled)
  short8 qf[2][2];
#pragma unroll
  for (int qt = 0; qt < 2; qt++)
#pragma unroll
    for (int kk = 0; kk < 2; kk++)
      qf[qt][kk] = *reinterpret_cast<const short8*>(
          qp + (size_t)(qr + qt * 16 + q15) * D_HEAD + kk * 32 + g * 8);

  f32x4 acc[2][4];  // [qt][dt]: O^T, col=q, row=d
#pragma unroll
  for (int qt = 0; qt < 2; qt++)
#pragma unroll
    for (int dt = 0; dt < 4; dt++) acc[qt][dt] = (f32x4){0.f, 0.f, 0.f, 0.f};
  float m_[2] = {-1e30f, -1e30f};
  float l_[2] = {0.f, 0.f};

  auto loadK = [&](int s0, short8 (&kf)[4][2]) {
#pragma unroll
    for (int st = 0; st < 4; st++) {
      const short* kr = kp + (size_t)(s0 + st * 16 + q15) * D_HEAD + g * 8;
      kf[st][0] = *reinterpret_cast<const short8*>(kr);
      kf[st][1] = *reinterpret_cast<const short8*>(kr + 32);
    }
  };

  // one 64-s chunk; issues next chunk's K loads early (nxt>=0) so their
  // latency hides under this chunk's softmax+PV.
  auto compute = [&](int s0, bool masked, short8 (&kf)[4][2], int nxt,
                     short8 (&knxt)[4][2]) {
    // V fragments issued first: consumed only after softmax (~latency hidden)
    short4v vf[4][4];
#pragma unroll
    for (int dt = 0; dt < 4; dt++)
#pragma unroll
      for (int st = 0; st < 4; st++)
        vf[dt][st] = *reinterpret_cast<const short4v*>(
            vp + (size_t)(dt * 16 + q15) * T_SEQ + s0 + st * 16 + g * 4);
    if (nxt >= 0) loadK(nxt, knxt);

    // S^T = K·Q^T: D[row=s][col=q]
    f32x4 sv[2][4];
    __builtin_amdgcn_s_setprio(1);
#pragma unroll
    for (int st = 0; st < 4; st++)
#pragma unroll
      for (int qt = 0; qt < 2; qt++) {
        f32x4 s = (f32x4){0.f, 0.f, 0.f, 0.f};
        s = __builtin_amdgcn_mfma_f32_16x16x32_bf16(kf[st][0], qf[qt][0], s, 0, 0, 0);
        s = __builtin_amdgcn_mfma_f32_16x16x32_bf16(kf[st][1], qf[qt][1], s, 0, 0, 0);
        sv[qt][st] = s;
      }
    __builtin_amdgcn_s_setprio(0);

    // causal mask (s <= q); Q was prescaled so no scale mul here
    if (masked) {
#pragma unroll
      for (int qt = 0; qt < 2; qt++)
#pragma unroll
        for (int st = 0; st < 4; st++)
#pragma unroll
          for (int r = 0; r < 4; r++) {
            int sg = s0 + st * 16 + g * 4 + r;
            if (sg > qr + qt * 16 + q15) sv[qt][st][r] = -1e30f;
          }
    }

    // online softmax per q-tile (lane-local + 2 shfl)
    short4v pb[2][4];
#pragma unroll
    for (int qt = 0; qt < 2; qt++) {
      float mx = sv[qt][0][0];
#pragma unroll
      for (int st = 0; st < 4; st++)
#pragma unroll
        for (int r = 0; r < 4; r++) mx = fmaxf(mx, sv[qt][st][r]);
      mx = fmaxf(mx, __shfl_xor(mx, 16));
      mx = fmaxf(mx, __shfl_xor(mx, 32));
      float mnew = fmaxf(m_[qt], mx);
      float sc   = __builtin_amdgcn_exp2f((m_[qt] - mnew) * LOG2E);
      m_[qt] = mnew;
      float ps = 0.f;
#pragma unroll
      for (int st = 0; st < 4; st++) {
#pragma unroll
        for (int r = 0; r < 4; r++) {
          float p = __builtin_amdgcn_exp2f((sv[qt][st][r] - mnew) * LOG2E);
          ps += p;
          pb[qt][st][r] = f2bf(p);
        }
      }
      ps += __shfl_xor(ps, 16);
      ps += __shfl_xor(ps, 32);
      l_[qt] = l_[qt] * sc + ps;
#pragma unroll
      for (int dt = 0; dt < 4; dt++) acc[qt][dt] *= sc;
    }

    // PV: O^T[d][q] += V^T[d][s] · P^T[s][q], 16-s tiles
    __builtin_amdgcn_s_setprio(1);
#pragma unroll
    for (int st = 0; st < 4; st++)
#pragma unroll
      for (int dt = 0; dt < 4; dt++)
#pragma unroll
        for (int qt = 0; qt < 2; qt++) {
#if __has_builtin(__builtin_amdgcn_mfma_f32_16x16x16bf16_1k)
          acc[qt][dt] = __builtin_amdgcn_mfma_f32_16x16x16bf16_1k(
              vf[dt][st], pb[qt][st], acc[qt][dt], 0, 0, 0);
#else
          short4v v4 = vf[dt][st];
          short4v p4 = pb[qt][st];
          short8 az = (short8){v4[0], v4[1], v4[2], v4[3], 0, 0, 0, 0};
          short8 bz = (short8){p4[0], p4[1], p4[2], p4[3], 0, 0, 0, 0};
          acc[qt][dt] =
              __builtin_amdgcn_mfma_f32_16x16x32_bf16(az, bz, acc[qt][dt], 0, 0, 0);
#endif
        }
    __builtin_amdgcn_s_setprio(0);
  };

  // main loop: K register double-buffer, static ping-pong indices
  short8 kA[4][2], kB[4][2];
  int nch = qr / 64 + 1;
  loadK(0, kA);
  int c = 0;
  while (true) {
    compute(c * 64, c + 1 == nch, kA, (c + 1 < nch) ? (c + 1) * 64 : -1, kB);
    if (++c == nch) break;
    compute(c * 64, c + 1 == nch, kB, (c + 1 < nch) ? (c + 1) * 64 : -1, kA);
    if (++c == nch) break;
  }

  // epilogue: per-wave LDS transpose -> coalesced bf16 stores
  __shared__ short Ol[4][32][68];
#pragma unroll
  for (int qt = 0; qt < 2; qt++) {
    float inv = 1.0f / l_[qt];
#pragma unroll
    for (int dt = 0; dt < 4; dt++)
#pragma unroll
      for (int r = 0; r < 4; r++)
        Ol[wv][qt * 16 + q15][dt * 16 + g * 4 + r] = f2bf(acc[qt][dt][r] * inv);
  }
  __syncthreads();
  int row = lane >> 1, cb = (lane & 1) * 32;
  size_t base = ((size_t)(b * T_SEQ) + qr + row) * C_DIM + h * 64 + cb;
#pragma unroll
  for (int i = 0; i < 4; i++)
    *reinterpret_cast<short8*>(ob + base + i * 8) =
        *reinterpret_cast<const short8*>(&Ol[wv][row][cb + i * 8]);
}

// ---------------------------------------------------------------------------
// Launch. Workspace layout (needs >= 40 MB):
//   [0, 8M)        xb   bf16 x cast            (reused as obuf after QKV GEMM)
//   [8M, 14.3M)    Wt   bf16 packed QKV weights [3072][1024]
//   [14M, 16M)     Wob  bf16 Wo [1024][1024]
//   [16M, 24M)     qb   bf16 [B,H,T,D]  (prescaled by 1/8)
//   [24M, 32M)     kb   bf16 [B,H,T,D]
//   [32M, 40M)     vtb  bf16 [B,H,D,T]
// ---------------------------------------------------------------------------
extern "C" void kernel_launch(void* const* d_in, const int* in_sizes, int n_in,
                              void* d_out, int out_size, void* d_ws, size_t ws_size,
                              hipStream_t stream) {
  const float* x  = (const float*)d_in[0];
  const float* Wq = (const float*)d_in[1];
  const float* Wk = (const float*)d_in[2];
  const float* Wv = (const float*)d_in[3];
  const float* Wo = (const float*)d_in[4];
  const float* bo = (const float*)d_in[5];
  float* out = (float*)d_out;

  char* ws = (char*)d_ws;
  short* xb   = (short*)(ws + 0);
  short* Wt   = (short*)(ws + 8388608);
  short* Wob  = (short*)(ws + 14680064);
  short* qb   = (short*)(ws + 16777216);
  short* kb   = (short*)(ws + 25165824);
  short* vtb  = (short*)(ws + 33554432);
  short* obuf = xb;  // reuse after QKV GEMM consumed xb

  cvt_f32_bf16<<<2048, 256, 0, stream>>>(x, xb, M_ROWS * C_DIM / 8);
  cvt_f32_bf16<<<512, 256, 0, stream>>>(Wo, Wob, C_DIM * C_DIM / 8);
  pack_w<<<768, 256, 0, stream>>>(Wq, Wk, Wv, Wt);

  gemm_bt<0><<<(M_ROWS / 128) * (N_QKV / 128), 256, 0, stream>>>(
      xb, Wt, nullptr, qb, kb, vtb, nullptr, M_ROWS, N_QKV, C_DIM);

  attn_fwd<<<B_DIM * H_NUM * (T_SEQ / 128), 256, 0, stream>>>(qb, kb, vtb, obuf);

  gemm_bt<1><<<(M_ROWS / 128) * (C_DIM / 128), 256, 0, stream>>>(
      obuf, Wob, bo, nullptr, nullptr, nullptr, out, M_ROWS, C_DIM, C_DIM);
}